// Round 1
// baseline (150.387 us; speedup 1.0000x reference)
//
#include <hip/hip_runtime.h>

#define TT 2048
#define DD 384

typedef float f32x4 __attribute__((ext_vector_type(4)));
typedef float f32x16 __attribute__((ext_vector_type(16)));
typedef short s16x8 __attribute__((ext_vector_type(8)));
typedef short s16x2 __attribute__((ext_vector_type(2)));
typedef unsigned int u32x4 __attribute__((ext_vector_type(4)));

typedef __attribute__((address_space(3))) unsigned char* as3p;
typedef const __attribute__((address_space(1))) unsigned char* as1p;
// HW direct global->LDS copy: 16B/lane x 64 lanes = 1KB per call; LDS dest = uniform base + lane*16.
#define GLLDS(gsrc, ldst) __builtin_amdgcn_global_load_lds((as1p)(gsrc), (as3p)(ldst), 16, 0, 0)

static __device__ __forceinline__ unsigned short f2bf(float f) {
    unsigned int u = __builtin_bit_cast(unsigned int, f);
    u = (u + 0x7fffu + ((u >> 16) & 1u)) >> 16;
    return (unsigned short)u;
}
static __device__ __forceinline__ unsigned int pk2(float a, float b) {
#if __has_builtin(__builtin_amdgcn_cvt_pk_bf16_f32)
    s16x2 t = __builtin_amdgcn_cvt_pk_bf16_f32(a, b);
    return __builtin_bit_cast(unsigned int, t);
#else
    unsigned int ua = __builtin_bit_cast(unsigned int, a);
    unsigned int ub = __builtin_bit_cast(unsigned int, b);
    ua = (ua + 0x7fffu + ((ua >> 16) & 1u)) >> 16;
    ub = (ub + 0x7fffu + ((ub >> 16) & 1u)) & 0xffff0000u;
    return ua | ub;
#endif
}

// ---------------- fused QKV projection GEMM, 128x128 tiles, inline fp32->bf16 ----------------
// nb=0 -> q (scaled 1/8, natural [t][64]) | k (PRE-SWIZZLED: within each row, 8-chunk c stored at c^(t&7));
// nb=1..3 -> v transposed vT[e][t], pre-swizzled within each 64-t block (chunk c at c^(e&7)).
// Pre-swizzle makes the attn kernel's global_load_lds image directly MFMA-read bank-balanced.
__global__ __launch_bounds__(256, 2) void qkv_gemm(
    const float* __restrict__ x, const float* __restrict__ Wq,
    const float* __restrict__ Wk, const float* __restrict__ Wv,
    unsigned short* __restrict__ qo, unsigned short* __restrict__ ko,
    unsigned short* __restrict__ vto)
{
    __shared__ __align__(16) unsigned short lds[16384];
    const int tid = threadIdx.x;
    const int l   = tid & 63;
    const int w   = tid >> 6;
    const int si  = l & 15;
    const int qq  = l >> 4;
    const int m0  = blockIdx.x * 128;
    const int nb  = blockIdx.y;
    const int wr  = w >> 1, wc = w & 1;

    const int bn = tid & 127;
    const int bk = (tid >> 7) * 16;
    const float* wsrc; int ldw;
    if (nb == 0) { wsrc = (bn < 64) ? (Wq + bn) : (Wk + (bn - 64)); ldw = 64; }
    else         { wsrc = Wv + (nb - 1) * 128 + bn;                 ldw = 384; }

    f32x4 acc[4][4];
    #pragma unroll
    for (int rt = 0; rt < 4; ++rt)
        #pragma unroll
        for (int ct = 0; ct < 4; ++ct) acc[rt][ct] = (f32x4){0.f, 0.f, 0.f, 0.f};

    for (int kt = 0; kt < 12; ++kt) {
        const int k0 = kt * 32;
        #pragma unroll
        for (int i = 0; i < 2; ++i) {
            const int u = tid + 256 * i, r = u >> 2, c = u & 3;
            const float* xp = x + (size_t)(m0 + r) * DD + k0 + c * 8;
            f32x4 x0 = *(const f32x4*)xp;
            f32x4 x1 = *(const f32x4*)(xp + 4);
            s16x8 av;
            av[0] = (short)f2bf(x0[0]); av[1] = (short)f2bf(x0[1]);
            av[2] = (short)f2bf(x0[2]); av[3] = (short)f2bf(x0[3]);
            av[4] = (short)f2bf(x1[0]); av[5] = (short)f2bf(x1[1]);
            av[6] = (short)f2bf(x1[2]); av[7] = (short)f2bf(x1[3]);
            *(s16x8*)&lds[r * 32 + ((c ^ (r & 3)) * 8)] = av;
        }
        {
            float t[16];
            #pragma unroll
            for (int j = 0; j < 16; ++j) t[j] = wsrc[(size_t)(k0 + bk + j) * ldw];
            #pragma unroll
            for (int jj = 0; jj < 2; ++jj) {
                s16x8 bv;
                #pragma unroll
                for (int j = 0; j < 8; ++j) bv[j] = (short)f2bf(t[jj * 8 + j]);
                const int ch = (tid >> 7) * 2 + jj;
                *(s16x8*)&lds[4096 + bn * 32 + ((ch ^ (bn & 3)) * 8)] = bv;
            }
        }
        __syncthreads();

        s16x8 af[4], bf[4];
        #pragma unroll
        for (int rt = 0; rt < 4; ++rt) {
            const int row = wr * 64 + rt * 16 + si;
            af[rt] = *(const s16x8*)&lds[row * 32 + ((qq ^ (row & 3)) * 8)];
        }
        #pragma unroll
        for (int ct = 0; ct < 4; ++ct) {
            const int col = wc * 64 + ct * 16 + si;
            bf[ct] = *(const s16x8*)&lds[4096 + col * 32 + ((qq ^ (col & 3)) * 8)];
        }
        #pragma unroll
        for (int rt = 0; rt < 4; ++rt)
            #pragma unroll
            for (int ct = 0; ct < 4; ++ct)
                acc[rt][ct] = __builtin_amdgcn_mfma_f32_16x16x32_bf16(af[rt], bf[ct], acc[rt][ct], 0, 0, 0);
        __syncthreads();
    }

    if (nb == 0) {
        if (wc == 0) {  // q: natural layout, fold 1/sqrt(K)
            #pragma unroll
            for (int rt = 0; rt < 4; ++rt)
                #pragma unroll
                for (int ct = 0; ct < 4; ++ct)
                    #pragma unroll
                    for (int r = 0; r < 4; ++r) {
                        const int m = m0 + wr * 64 + rt * 16 + qq * 4 + r;
                        qo[(size_t)m * 64 + ct * 16 + si] = f2bf(acc[rt][ct][r] * 0.125f);
                    }
        } else {        // k: pre-swizzled (chunk c -> c ^ (t&7))
            #pragma unroll
            for (int rt = 0; rt < 4; ++rt)
                #pragma unroll
                for (int ct = 0; ct < 4; ++ct)
                    #pragma unroll
                    for (int r = 0; r < 4; ++r) {
                        const int m = m0 + wr * 64 + rt * 16 + qq * 4 + r;
                        const int col = ct * 16 + si;
                        ko[(size_t)m * 64 + (((col >> 3) ^ (m & 7)) * 8) + (col & 7)] = f2bf(acc[rt][ct][r]);
                    }
        }
    } else {
        #pragma unroll
        for (int rt = 0; rt < 4; ++rt)
            #pragma unroll
            for (int ct = 0; ct < 4; ++ct)
                #pragma unroll
                for (int r = 0; r < 4; ++r) {
                    const int m = wr * 64 + rt * 16 + qq * 4 + r;
                    const int n = wc * 64 + ct * 16 + si;
                    lds[n * 128 + (((m >> 3) ^ (n & 7)) * 8) + (m & 7)] = f2bf(acc[rt][ct][r]);
                }
        __syncthreads();
        const int bbat = m0 >> 11, t0 = m0 & 2047;
        #pragma unroll
        for (int i = 0; i < 8; ++i) {
            const int u = tid + 256 * i, n = u >> 4, mc = u & 15;
            s16x8 v = *(const s16x8*)&lds[n * 128 + ((mc ^ (n & 7)) * 8)];
            // pre-swizzle within each 64-t block: chunk (mc&7) stored at (mc&7)^(e&7); e&7 == n&7
            *(s16x8*)&vto[((size_t)bbat * DD + ((nb - 1) * 128 + n)) * TT
                          + t0 + (mc >> 3) * 64 + (((mc & 7) ^ (n & 7)) * 8)] = v;
        }
    }
}

// ---------------- flash attention, causal, 1024-thr, 4-way s-split, async dbuf staging ----------------
// R6: double TLP. Same 80KB LDS image & swizzles as R5, but 16 waves/block: wave = (q4, qb),
// q4 = s-quarter (h = q4>>1 picks the K/V LDS half, ct = q4&1 the 32-col subtile), qb = 32-row q-band.
// VGPR+AGPR ~112 <= 128 -> 4 waves/SIMD resident (1 block/CU), vs 2.1 avg before (latency-bound fix).
// Grid 512, j DESCENDING (LPT): first 256 blocks j=15..8 start everywhere; CUs backfill j=7..0 in
// order -> every CU ~17 tile-units. 32-wide guard also prunes fully-masked diagonal subtiles.
// Epilogue: 4-way partial combine, 2 phases (bands 0-1, then 2-3), 6 writer + 2 reader waves each.
__global__ __launch_bounds__(1024, 4) void attn(
    const unsigned short* __restrict__ qg, const unsigned short* __restrict__ kg,
    const unsigned short* __restrict__ vg, float* __restrict__ out)
{
    // bytes: K dbuf [0,32768) = 2 x [128 t][128B] | V dbuf [32768,81920) = 2 x [2 half][96 e][128B]
    // post-loop overlay: stL fp32 [0,2048) + fb fp32 [2048, 75776)
    __shared__ __align__(16) unsigned short lds[40960];

    const int tid = threadIdx.x;
    const int l   = tid & 63;
    const int w   = tid >> 6;    // 0..15
    const int q4  = w >> 2;      // s-quarter 0..3
    const int qb  = w & 3;       // q-band (32 rows)
    const int lo  = l & 31;
    const int hi  = l >> 5;
    const int h   = q4 >> 1;     // K/V LDS half (64-t)
    const int ct  = q4 & 1;      // 32-col subtile within half

    const int g  = blockIdx.x;
    const int bb = g & 7;              // batch on low bits: one batch per XCD -> K/V L2-resident
    const int eq = (g >> 3) & 3;
    const int j  = 15 - (g >> 5);      // LPT: longest blocks dispatched first
    const int q0 = j * 128;
    const int e0 = eq * 96;
    const int qrow = q0 + qb * 32 + lo;

    // Q as B-operand frags (q pre-scaled by 1/8 in qkv; natural layout)
    s16x8 qf[4];
    {
        const unsigned short* qp = qg + ((size_t)bb * TT + qrow) * 64;
        #pragma unroll
        for (int st = 0; st < 4; ++st) qf[st] = *(const s16x8*)(qp + st * 16 + hi * 8);
    }

    f32x16 o[3];
    #pragma unroll
    for (int et = 0; et < 3; ++et)
        #pragma unroll
        for (int r = 0; r < 16; ++r) o[et][r] = 0.f;
    float lp = 0.f;

    // ---- async staging: 16 K-chunks + 24 V-chunks (1KB each) over 16 waves ----
    const unsigned short* kbase = kg + (size_t)bb * TT * 64;
    const unsigned short* vbase = vg + ((size_t)bb * DD + e0) * TT;

    // loop-invariant per-thread source pointers (strength-reduced: +IT stride per call)
    const unsigned short* kS = kbase + w * 512 + l * 8;                       // + IT*8192
    const int chA = w,      pA = chA / 12, rrA = (chA % 12) * 8;
    const int chB = 16 + w, pB = chB / 12, rrB = (chB % 12) * 8;
    const unsigned short* vSA = vbase + ((size_t)(rrA + (l >> 3))) * TT + pA * 64 + (l & 7) * 8;  // + IT*128
    const unsigned short* vSB = vbase + ((size_t)(rrB + (l >> 3))) * TT + pB * 64 + (l & 7) * 8;

    #define STAGE(IT, BUF)                                                   \
    {                                                                        \
        unsigned short* kl = &lds[(BUF) * 8192];                             \
        GLLDS(kS + (size_t)(IT) * 8192, &kl[w * 512]);                       \
        unsigned short* vl = &lds[16384 + (BUF) * 12288];                    \
        GLLDS(vSA + (IT) * 128, &vl[chA * 512]);                             \
        if (w < 8) GLLDS(vSB + (IT) * 128, &vl[chB * 512]);                  \
    }

    STAGE(0, 0);   // prologue

    for (int it = 0; it <= j; ++it) {
        const int buf = it & 1;
        __syncthreads();   // vmcnt(0)+barrier: copies into buf complete; all waves done with 1-buf

        if (it < j) STAGE(it + 1, 1 - buf);   // fly during compute

        const unsigned short* Ks = &lds[buf * 8192 + h * 4096];
        const unsigned short* Vs = &lds[16384 + buf * 12288 + h * 6144];

        const int sq = it * 128 + q4 * 32;
        if (sq <= q0 + qb * 32 + 31) {        // also prunes fully-masked diagonal subtiles
            const bool mb = (sq + 31 > q0 + qb * 32);
            f32x16 sa;
            #pragma unroll
            for (int r = 0; r < 16; ++r) sa[r] = 0.f;
            #pragma unroll
            for (int st = 0; st < 4; ++st) {
                s16x8 kf = *(const s16x8*)&Ks[(ct * 32 + lo) * 64 + (((st * 2 + hi) ^ (lo & 7)) * 8)];
                sa = __builtin_amdgcn_mfma_f32_32x32x16_bf16(kf, qf[st], sa, 0, 0, 0);
            }
            float pv[16];
            #pragma unroll
            for (int r = 0; r < 16; ++r) {
                float e = __expf(sa[r]);
                if (mb) {
                    const int srow = sq + (r & 3) + 8 * (r >> 2) + 4 * hi;
                    if (srow > qrow) e = 0.f;
                }
                pv[r] = e;
                lp += e;
            }
            unsigned int d0 = pk2(pv[0], pv[1]),   d1 = pk2(pv[2], pv[3]);
            unsigned int d2 = pk2(pv[4], pv[5]),   d3 = pk2(pv[6], pv[7]);
            unsigned int d4 = pk2(pv[8], pv[9]),   d5 = pk2(pv[10], pv[11]);
            unsigned int d6 = pk2(pv[12], pv[13]), d7 = pk2(pv[14], pv[15]);
            unsigned int sA0 = hi ? d0 : d2, sA1 = hi ? d1 : d3;
            unsigned int rA0 = (unsigned int)__shfl_xor((int)sA0, 32);
            unsigned int rA1 = (unsigned int)__shfl_xor((int)sA1, 32);
            u32x4 fa0 = hi ? (u32x4){rA0, rA1, d2, d3} : (u32x4){d0, d1, rA0, rA1};
            unsigned int sB0 = hi ? d4 : d6, sB1 = hi ? d5 : d7;
            unsigned int rB0 = (unsigned int)__shfl_xor((int)sB0, 32);
            unsigned int rB1 = (unsigned int)__shfl_xor((int)sB1, 32);
            u32x4 fa1 = hi ? (u32x4){rB0, rB1, d6, d7} : (u32x4){d4, d5, rB0, rB1};
            s16x8 a0 = __builtin_bit_cast(s16x8, fa0);
            s16x8 a1 = __builtin_bit_cast(s16x8, fa1);
            #pragma unroll
            for (int et = 0; et < 3; ++et) {
                const int el = et * 32 + lo;
                s16x8 v0 = *(const s16x8*)&Vs[el * 64 + (((ct * 4 + hi) ^ (el & 7)) * 8)];
                o[et] = __builtin_amdgcn_mfma_f32_32x32x16_bf16(a0, v0, o[et], 0, 0, 0);
                s16x8 v1 = *(const s16x8*)&Vs[el * 64 + (((ct * 4 + 2 + hi) ^ (el & 7)) * 8)];
                o[et] = __builtin_amdgcn_mfma_f32_32x32x16_bf16(a1, v1, o[et], 0, 0, 0);
            }
        }
    }
    __syncthreads();   // loop ends on compute: drain before overlaying buffers

    // l totals per quarter -> stL (overlaid at bytes [0, 2048))
    float* stL = (float*)lds;          // [4][128]
    float* fb  = (float*)lds + 512;    // [3][64][96] staged partials (two bands per phase)
    lp += __shfl_xor(lp, 32);
    if (hi == 0) stL[q4 * 128 + qb * 32 + lo] = lp;
    __syncthreads();

    // combine 4 partials (2 phases of 2 q-bands), normalize, store
    #pragma unroll
    for (int ph = 0; ph < 2; ++ph) {
        if (q4 != 0 && (qb >> 1) == ph) {
            const int slot = (q4 - 1) * 64 + (qb & 1) * 32;
            #pragma unroll
            for (int r = 0; r < 16; ++r) {
                const int rloc = (r & 3) + 8 * (r >> 2) + 4 * hi;
                #pragma unroll
                for (int et = 0; et < 3; ++et)
                    fb[(slot + rloc) * 96 + et * 32 + lo] = o[et][r];
            }
        }
        __syncthreads();
        if (q4 == 0 && (qb >> 1) == ph) {
            const int slot = (qb & 1) * 32;
            #pragma unroll
            for (int r = 0; r < 16; ++r) {
                const int rloc = (r & 3) + 8 * (r >> 2) + 4 * hi;
                const int rr = qb * 32 + rloc;
                const float linv = 1.f / (stL[rr] + stL[128 + rr] + stL[256 + rr] + stL[384 + rr]);
                float* op = out + ((size_t)bb * TT + q0 + rr) * DD + e0;
                #pragma unroll
                for (int et = 0; et < 3; ++et)
                    op[et * 32 + lo] = (o[et][r]
                        + fb[(0 * 64 + slot + rloc) * 96 + et * 32 + lo]
                        + fb[(1 * 64 + slot + rloc) * 96 + et * 32 + lo]
                        + fb[(2 * 64 + slot + rloc) * 96 + et * 32 + lo]) * linv;
            }
        }
        __syncthreads();
    }
    #undef STAGE
}

extern "C" void kernel_launch(void* const* d_in, const int* in_sizes, int n_in,
                              void* d_out, int out_size, void* d_ws, size_t ws_size,
                              hipStream_t stream)
{
    const float* x  = (const float*)d_in[0];
    const float* Wq = (const float*)d_in[1];
    const float* Wk = (const float*)d_in[2];
    const float* Wv = (const float*)d_in[3];

    // ws: q [0,2M) | k [2M,4M) | vT [4M,16M)
    unsigned short* qws  = (unsigned short*)d_ws;
    unsigned short* kws  = (unsigned short*)((char*)d_ws + ((size_t)2 << 20));
    unsigned short* vtws = (unsigned short*)((char*)d_ws + ((size_t)4 << 20));

    qkv_gemm<<<dim3(128, 4), dim3(256), 0, stream>>>(x, Wq, Wk, Wv, qws, kws, vtws);
    attn<<<dim3(512), dim3(1024), 0, stream>>>(qws, kws, vtws, (float*)d_out);
}

// Round 2
// 150.177 us; speedup vs baseline: 1.0014x; 1.0014x over previous
//
#include <hip/hip_runtime.h>

#define TT 2048
#define DD 384

typedef float f32x4 __attribute__((ext_vector_type(4)));
typedef float f32x16 __attribute__((ext_vector_type(16)));
typedef short s16x8 __attribute__((ext_vector_type(8)));
typedef short s16x2 __attribute__((ext_vector_type(2)));
typedef unsigned int u32x4 __attribute__((ext_vector_type(4)));

typedef __attribute__((address_space(3))) unsigned char* as3p;
typedef const __attribute__((address_space(1))) unsigned char* as1p;
// HW direct global->LDS copy: 16B/lane x 64 lanes = 1KB per call; LDS dest = uniform base + lane*16.
#define GLLDS(gsrc, ldst) __builtin_amdgcn_global_load_lds((as1p)(gsrc), (as3p)(ldst), 16, 0, 0)

static __device__ __forceinline__ unsigned short f2bf(float f) {
    unsigned int u = __builtin_bit_cast(unsigned int, f);
    u = (u + 0x7fffu + ((u >> 16) & 1u)) >> 16;
    return (unsigned short)u;
}
static __device__ __forceinline__ unsigned int pk2(float a, float b) {
#if __has_builtin(__builtin_amdgcn_cvt_pk_bf16_f32)
    s16x2 t = __builtin_amdgcn_cvt_pk_bf16_f32(a, b);
    return __builtin_bit_cast(unsigned int, t);
#else
    unsigned int ua = __builtin_bit_cast(unsigned int, a);
    unsigned int ub = __builtin_bit_cast(unsigned int, b);
    ua = (ua + 0x7fffu + ((ua >> 16) & 1u)) >> 16;
    ub = (ub + 0x7fffu + ((ub >> 16) & 1u)) & 0xffff0000u;
    return ua | ub;
#endif
}

// ---------------- fused QKV projection GEMM, 128x128 tiles, inline fp32->bf16 ----------------
// nb=0 -> q (scaled 1/8, natural [t][64]) | k (PRE-SWIZZLED: within each row, 8-chunk c stored at c^(t&7));
// nb=1..3 -> v transposed vT[e][t], pre-swizzled within each 64-t block (chunk c at c^(e&7)).
__global__ __launch_bounds__(256, 2) void qkv_gemm(
    const float* __restrict__ x, const float* __restrict__ Wq,
    const float* __restrict__ Wk, const float* __restrict__ Wv,
    unsigned short* __restrict__ qo, unsigned short* __restrict__ ko,
    unsigned short* __restrict__ vto)
{
    __shared__ __align__(16) unsigned short lds[16384];
    const int tid = threadIdx.x;
    const int l   = tid & 63;
    const int w   = tid >> 6;
    const int si  = l & 15;
    const int qq  = l >> 4;
    const int m0  = blockIdx.x * 128;
    const int nb  = blockIdx.y;
    const int wr  = w >> 1, wc = w & 1;

    const int bn = tid & 127;
    const int bk = (tid >> 7) * 16;
    const float* wsrc; int ldw;
    if (nb == 0) { wsrc = (bn < 64) ? (Wq + bn) : (Wk + (bn - 64)); ldw = 64; }
    else         { wsrc = Wv + (nb - 1) * 128 + bn;                 ldw = 384; }

    f32x4 acc[4][4];
    #pragma unroll
    for (int rt = 0; rt < 4; ++rt)
        #pragma unroll
        for (int ct = 0; ct < 4; ++ct) acc[rt][ct] = (f32x4){0.f, 0.f, 0.f, 0.f};

    for (int kt = 0; kt < 12; ++kt) {
        const int k0 = kt * 32;
        #pragma unroll
        for (int i = 0; i < 2; ++i) {
            const int u = tid + 256 * i, r = u >> 2, c = u & 3;
            const float* xp = x + (size_t)(m0 + r) * DD + k0 + c * 8;
            f32x4 x0 = *(const f32x4*)xp;
            f32x4 x1 = *(const f32x4*)(xp + 4);
            s16x8 av;
            av[0] = (short)f2bf(x0[0]); av[1] = (short)f2bf(x0[1]);
            av[2] = (short)f2bf(x0[2]); av[3] = (short)f2bf(x0[3]);
            av[4] = (short)f2bf(x1[0]); av[5] = (short)f2bf(x1[1]);
            av[6] = (short)f2bf(x1[2]); av[7] = (short)f2bf(x1[3]);
            *(s16x8*)&lds[r * 32 + ((c ^ (r & 3)) * 8)] = av;
        }
        {
            float t[16];
            #pragma unroll
            for (int j = 0; j < 16; ++j) t[j] = wsrc[(size_t)(k0 + bk + j) * ldw];
            #pragma unroll
            for (int jj = 0; jj < 2; ++jj) {
                s16x8 bv;
                #pragma unroll
                for (int j = 0; j < 8; ++j) bv[j] = (short)f2bf(t[jj * 8 + j]);
                const int ch = (tid >> 7) * 2 + jj;
                *(s16x8*)&lds[4096 + bn * 32 + ((ch ^ (bn & 3)) * 8)] = bv;
            }
        }
        __syncthreads();

        s16x8 af[4], bf[4];
        #pragma unroll
        for (int rt = 0; rt < 4; ++rt) {
            const int row = wr * 64 + rt * 16 + si;
            af[rt] = *(const s16x8*)&lds[row * 32 + ((qq ^ (row & 3)) * 8)];
        }
        #pragma unroll
        for (int ct = 0; ct < 4; ++ct) {
            const int col = wc * 64 + ct * 16 + si;
            bf[ct] = *(const s16x8*)&lds[4096 + col * 32 + ((qq ^ (col & 3)) * 8)];
        }
        #pragma unroll
        for (int rt = 0; rt < 4; ++rt)
            #pragma unroll
            for (int ct = 0; ct < 4; ++ct)
                acc[rt][ct] = __builtin_amdgcn_mfma_f32_16x16x32_bf16(af[rt], bf[ct], acc[rt][ct], 0, 0, 0);
        __syncthreads();
    }

    if (nb == 0) {
        if (wc == 0) {  // q: natural layout, fold 1/sqrt(K)
            #pragma unroll
            for (int rt = 0; rt < 4; ++rt)
                #pragma unroll
                for (int ct = 0; ct < 4; ++ct)
                    #pragma unroll
                    for (int r = 0; r < 4; ++r) {
                        const int m = m0 + wr * 64 + rt * 16 + qq * 4 + r;
                        qo[(size_t)m * 64 + ct * 16 + si] = f2bf(acc[rt][ct][r] * 0.125f);
                    }
        } else {        // k: pre-swizzled (chunk c -> c ^ (t&7))
            #pragma unroll
            for (int rt = 0; rt < 4; ++rt)
                #pragma unroll
                for (int ct = 0; ct < 4; ++ct)
                    #pragma unroll
                    for (int r = 0; r < 4; ++r) {
                        const int m = m0 + wr * 64 + rt * 16 + qq * 4 + r;
                        const int col = ct * 16 + si;
                        ko[(size_t)m * 64 + (((col >> 3) ^ (m & 7)) * 8) + (col & 7)] = f2bf(acc[rt][ct][r]);
                    }
        }
    } else {
        #pragma unroll
        for (int rt = 0; rt < 4; ++rt)
            #pragma unroll
            for (int ct = 0; ct < 4; ++ct)
                #pragma unroll
                for (int r = 0; r < 4; ++r) {
                    const int m = wr * 64 + rt * 16 + qq * 4 + r;
                    const int n = wc * 64 + ct * 16 + si;
                    lds[n * 128 + (((m >> 3) ^ (n & 7)) * 8) + (m & 7)] = f2bf(acc[rt][ct][r]);
                }
        __syncthreads();
        const int bbat = m0 >> 11, t0 = m0 & 2047;
        #pragma unroll
        for (int i = 0; i < 8; ++i) {
            const int u = tid + 256 * i, n = u >> 4, mc = u & 15;
            s16x8 v = *(const s16x8*)&lds[n * 128 + ((mc ^ (n & 7)) * 8)];
            *(s16x8*)&vto[((size_t)bbat * DD + ((nb - 1) * 128 + n)) * TT
                          + t0 + (mc >> 3) * 64 + (((mc & 7) ^ (n & 7)) * 8)] = v;
        }
    }
}

// ---------------- pass 1: QK^T + exp, computed ONCE per causal tile ----------------
// One block per causal 128x128 tile (t -> (j, it) triangular). 256 thr, wave w = q-band.
// Stores the ready-to-use PV A-fragments (a0/a1, 32B/lane/subtile) + per-(row,tile) l-partials.
// P tile layout: tile*16384 ush; subtile (qb,sq): +(qb*4+sq)*1024; a0 at +l*8, a1 at +512+l*8.
__global__ __launch_bounds__(256, 4) void qk_pass(
    const unsigned short* __restrict__ qg, const unsigned short* __restrict__ kg,
    unsigned short* __restrict__ Pws, float* __restrict__ lpart)
{
    __shared__ __align__(16) unsigned short kl[8192];   // K tile [128 t][64], pre-swizzled image
    const int tid = threadIdx.x;
    const int l   = tid & 63;
    const int w   = tid >> 6;    // q-band 0..3
    const int lo  = l & 31;
    const int hi  = l >> 5;
    const int t   = blockIdx.x;  // 0..135 triangular tile id
    const int bb  = blockIdx.y;

    int j = 0, acc = 0;
    while (acc + j + 1 <= t) { acc += j + 1; ++j; }
    const int it = t - acc;

    const unsigned short* kS = kg + (size_t)bb * TT * 64 + (size_t)it * 8192;
    #pragma unroll
    for (int c = 0; c < 4; ++c)
        GLLDS(kS + (w * 4 + c) * 512 + l * 8, &kl[(w * 4 + c) * 512]);

    const int qrow = j * 128 + w * 32 + lo;
    s16x8 qf[4];
    {
        const unsigned short* qp = qg + ((size_t)bb * TT + qrow) * 64;
        #pragma unroll
        for (int st = 0; st < 4; ++st) qf[st] = *(const s16x8*)(qp + st * 16 + hi * 8);
    }

    __syncthreads();

    float lp = 0.f;
    const bool onD = (it == j);
    unsigned short* pt = Pws + (size_t)(bb * 136 + t) * 16384;
    const int nsq = onD ? (w + 1) : 4;   // fully-masked diagonal subtiles never computed/stored
    for (int sq = 0; sq < nsq; ++sq) {
        f32x16 sa;
        #pragma unroll
        for (int r = 0; r < 16; ++r) sa[r] = 0.f;
        #pragma unroll
        for (int st = 0; st < 4; ++st) {
            s16x8 kf = *(const s16x8*)&kl[(sq * 32 + lo) * 64 + (((st * 2 + hi) ^ (lo & 7)) * 8)];
            sa = __builtin_amdgcn_mfma_f32_32x32x16_bf16(kf, qf[st], sa, 0, 0, 0);
        }
        const bool mb = onD && (sq == w);
        float pv[16];
        #pragma unroll
        for (int r = 0; r < 16; ++r) {
            float e = __expf(sa[r]);
            if (mb) {
                const int srow = it * 128 + sq * 32 + (r & 3) + 8 * (r >> 2) + 4 * hi;
                if (srow > qrow) e = 0.f;
            }
            pv[r] = e;
            lp += e;
        }
        unsigned int d0 = pk2(pv[0], pv[1]),   d1 = pk2(pv[2], pv[3]);
        unsigned int d2 = pk2(pv[4], pv[5]),   d3 = pk2(pv[6], pv[7]);
        unsigned int d4 = pk2(pv[8], pv[9]),   d5 = pk2(pv[10], pv[11]);
        unsigned int d6 = pk2(pv[12], pv[13]), d7 = pk2(pv[14], pv[15]);
        unsigned int sA0 = hi ? d0 : d2, sA1 = hi ? d1 : d3;
        unsigned int rA0 = (unsigned int)__shfl_xor((int)sA0, 32);
        unsigned int rA1 = (unsigned int)__shfl_xor((int)sA1, 32);
        u32x4 fa0 = hi ? (u32x4){rA0, rA1, d2, d3} : (u32x4){d0, d1, rA0, rA1};
        unsigned int sB0 = hi ? d4 : d6, sB1 = hi ? d5 : d7;
        unsigned int rB0 = (unsigned int)__shfl_xor((int)sB0, 32);
        unsigned int rB1 = (unsigned int)__shfl_xor((int)sB1, 32);
        u32x4 fa1 = hi ? (u32x4){rB0, rB1, d6, d7} : (u32x4){d4, d5, rB0, rB1};
        *(s16x8*)(pt + (w * 4 + sq) * 1024 + l * 8)       = __builtin_bit_cast(s16x8, fa0);
        *(s16x8*)(pt + (w * 4 + sq) * 1024 + 512 + l * 8) = __builtin_bit_cast(s16x8, fa1);
    }
    lp += __shfl_xor(lp, 32);
    if (hi == 0)
        lpart[((size_t)bb * 16 + it) * 2048 + (size_t)j * 128 + w * 32 + lo] = lp;
}

// ---------------- pass 2: PV dense GEMM over the causal band + normalize ----------------
// Grid 384 = 8 bb x 3 e-slices(128) x 16 j, snake-paired so (big j, small j) co-reside per CU.
// 512 thr, 8 waves: wave = (qb: 32 q-rows) x (ew: 64 e-cols). V double-buffered in LDS (64KB ->
// 2 blocks/CU); P fragments read lane-linear straight from L2/L3 (no LDS, no shuffle).
__global__ __launch_bounds__(512, 4) void pv_pass(
    const unsigned short* __restrict__ Pws, const unsigned short* __restrict__ vg,
    const float* __restrict__ lpart, float* __restrict__ out)
{
    __shared__ __align__(16) unsigned short vl[32768];   // 2 x [2 half][128 e][64], pre-swizzled
    __shared__ float linv[128];
    const int tid = threadIdx.x;
    const int l   = tid & 63;
    const int w   = tid >> 6;    // 0..7
    const int qb  = w >> 1;
    const int ew  = w & 1;
    const int lo  = l & 31;
    const int hi  = l >> 5;

    const int g  = blockIdx.x;   // 0..383
    const int m  = g >> 1, p = g & 1;
    const int jj = m / 12;
    const int j  = p ? jj : 15 - jj;        // pair (2m,2m+1) and (c,c+256) both sum ~const work
    const int combo = (m % 12) * 2 + p;     // 0..23 unique per j
    const int bb = combo & 7;
    const int eb = combo >> 3;              // 0..2

    const unsigned short* ptile = Pws + (size_t)(bb * 136 + j * (j + 1) / 2) * 16384;
    const unsigned short* vbase = vg + ((size_t)bb * DD + eb * 128) * TT;

    if (tid < 128) {            // row-sum of l-partials -> 1/l
        float s = 0.f;
        for (int it = 0; it <= j; ++it)
            s += lpart[((size_t)bb * 16 + it) * 2048 + (size_t)j * 128 + tid];
        linv[tid] = 1.f / s;
    }

    const unsigned short* vS[4];
    #pragma unroll
    for (int c = 0; c < 4; ++c) {
        const int ch = w * 4 + c, ph = ch >> 4, rg = ch & 15;
        vS[c] = vbase + (size_t)(rg * 8 + (l >> 3)) * TT + ph * 64 + (l & 7) * 8;
    }
    #define VSTAGE(IT, BUF)                                                     \
    {                                                                           \
        _Pragma("unroll")                                                       \
        for (int c = 0; c < 4; ++c)                                             \
            GLLDS(vS[c] + (size_t)(IT) * 128, &vl[(BUF) * 16384 + (w * 4 + c) * 512]); \
    }

    f32x16 o[2];
    #pragma unroll
    for (int et = 0; et < 2; ++et)
        #pragma unroll
        for (int r = 0; r < 16; ++r) o[et][r] = 0.f;

    VSTAGE(0, 0);
    for (int it = 0; it <= j; ++it) {
        const int buf = it & 1;
        __syncthreads();                      // vmcnt(0)+barrier: buf ready, other buf free
        if (it < j) VSTAGE(it + 1, 1 - buf);  // fly during compute

        const unsigned short* pfr = ptile + (size_t)it * 16384 + qb * 4096;
        const int nsq = (it == j) ? (qb + 1) : 4;   // skip fully-masked diagonal subtiles
        for (int sq = 0; sq < nsq; ++sq) {
            s16x8 a0 = *(const s16x8*)(pfr + sq * 1024 + l * 8);
            s16x8 a1 = *(const s16x8*)(pfr + sq * 1024 + 512 + l * 8);
            const int h = sq >> 1, ct = sq & 1;
            const unsigned short* Vs = &vl[buf * 16384 + h * 8192];
            #pragma unroll
            for (int et = 0; et < 2; ++et) {
                const int el = ew * 64 + et * 32 + lo;
                s16x8 v0 = *(const s16x8*)&Vs[el * 64 + (((ct * 4 + hi) ^ (el & 7)) * 8)];
                o[et] = __builtin_amdgcn_mfma_f32_32x32x16_bf16(a0, v0, o[et], 0, 0, 0);
                s16x8 v1 = *(const s16x8*)&Vs[el * 64 + (((ct * 4 + 2 + hi) ^ (el & 7)) * 8)];
                o[et] = __builtin_amdgcn_mfma_f32_32x32x16_bf16(a1, v1, o[et], 0, 0, 0);
            }
        }
    }
    #undef VSTAGE

    #pragma unroll
    for (int et = 0; et < 2; ++et)
        #pragma unroll
        for (int r = 0; r < 16; ++r) {
            const int rloc = (r & 3) + 8 * (r >> 2) + 4 * hi;
            const int row  = qb * 32 + rloc;
            out[((size_t)bb * TT + j * 128 + row) * DD + eb * 128 + ew * 64 + et * 32 + lo]
                = o[et][r] * linv[row];
        }
}

extern "C" void kernel_launch(void* const* d_in, const int* in_sizes, int n_in,
                              void* d_out, int out_size, void* d_ws, size_t ws_size,
                              hipStream_t stream)
{
    const float* x  = (const float*)d_in[0];
    const float* Wq = (const float*)d_in[1];
    const float* Wk = (const float*)d_in[2];
    const float* Wv = (const float*)d_in[3];

    // ws: q [0,2M) | k [2M,4M) | vT [4M,16M) | P frags [16M, 16M+34M) | lpart [+1M)
    unsigned short* qws  = (unsigned short*)d_ws;
    unsigned short* kws  = (unsigned short*)((char*)d_ws + ((size_t)2 << 20));
    unsigned short* vtws = (unsigned short*)((char*)d_ws + ((size_t)4 << 20));
    unsigned short* Pws  = (unsigned short*)((char*)d_ws + ((size_t)16 << 20));
    float*          lpart = (float*)((char*)d_ws + ((size_t)16 << 20) + (size_t)8 * 136 * 32768);

    qkv_gemm<<<dim3(128, 4), dim3(256), 0, stream>>>(x, Wq, Wk, Wv, qws, kws, vtws);
    qk_pass<<<dim3(136, 8), dim3(256), 0, stream>>>(qws, kws, Pws, lpart);
    pv_pass<<<dim3(384), dim3(512), 0, stream>>>(Pws, vtws, lpart, (float*)d_out);
}

// Round 3
// 140.261 us; speedup vs baseline: 1.0722x; 1.0707x over previous
//
#include <hip/hip_runtime.h>

#define TT 2048
#define DD 384

typedef float f32x4 __attribute__((ext_vector_type(4)));
typedef float f32x16 __attribute__((ext_vector_type(16)));
typedef short s16x8 __attribute__((ext_vector_type(8)));
typedef short s16x2 __attribute__((ext_vector_type(2)));
typedef unsigned int u32x4 __attribute__((ext_vector_type(4)));

typedef __attribute__((address_space(3))) unsigned char* as3p;
typedef const __attribute__((address_space(1))) unsigned char* as1p;
// HW direct global->LDS copy: 16B/lane x 64 lanes = 1KB per call; LDS dest = uniform base + lane*16.
#define GLLDS(gsrc, ldst) __builtin_amdgcn_global_load_lds((as1p)(gsrc), (as3p)(ldst), 16, 0, 0)

static __device__ __forceinline__ unsigned short f2bf(float f) {
    unsigned int u = __builtin_bit_cast(unsigned int, f);
    u = (u + 0x7fffu + ((u >> 16) & 1u)) >> 16;
    return (unsigned short)u;
}
static __device__ __forceinline__ unsigned int pk2(float a, float b) {
#if __has_builtin(__builtin_amdgcn_cvt_pk_bf16_f32)
    s16x2 t = __builtin_amdgcn_cvt_pk_bf16_f32(a, b);
    return __builtin_bit_cast(unsigned int, t);
#else
    unsigned int ua = __builtin_bit_cast(unsigned int, a);
    unsigned int ub = __builtin_bit_cast(unsigned int, b);
    ua = (ua + 0x7fffu + ((ua >> 16) & 1u)) >> 16;
    ub = (ub + 0x7fffu + ((ub >> 16) & 1u)) & 0xffff0000u;
    return ua | ub;
#endif
}

// ---------------- fused QKV projection GEMM, 128x128 tiles, inline fp32->bf16 ----------------
// nb=0 -> q (scaled 1/8, natural [t][64]) | k (PRE-SWIZZLED: within each row, 8-chunk c stored at c^(t&7));
// nb=1..3 -> v transposed vT[e][t], pre-swizzled within each 64-t block (chunk c at c^(e&7)).
__global__ __launch_bounds__(256, 2) void qkv_gemm(
    const float* __restrict__ x, const float* __restrict__ Wq,
    const float* __restrict__ Wk, const float* __restrict__ Wv,
    unsigned short* __restrict__ qo, unsigned short* __restrict__ ko,
    unsigned short* __restrict__ vto)
{
    __shared__ __align__(16) unsigned short lds[16384];
    const int tid = threadIdx.x;
    const int l   = tid & 63;
    const int w   = tid >> 6;
    const int si  = l & 15;
    const int qq  = l >> 4;
    const int m0  = blockIdx.x * 128;
    const int nb  = blockIdx.y;
    const int wr  = w >> 1, wc = w & 1;

    const int bn = tid & 127;
    const int bk = (tid >> 7) * 16;
    const float* wsrc; int ldw;
    if (nb == 0) { wsrc = (bn < 64) ? (Wq + bn) : (Wk + (bn - 64)); ldw = 64; }
    else         { wsrc = Wv + (nb - 1) * 128 + bn;                 ldw = 384; }

    f32x4 acc[4][4];
    #pragma unroll
    for (int rt = 0; rt < 4; ++rt)
        #pragma unroll
        for (int ct = 0; ct < 4; ++ct) acc[rt][ct] = (f32x4){0.f, 0.f, 0.f, 0.f};

    for (int kt = 0; kt < 12; ++kt) {
        const int k0 = kt * 32;
        #pragma unroll
        for (int i = 0; i < 2; ++i) {
            const int u = tid + 256 * i, r = u >> 2, c = u & 3;
            const float* xp = x + (size_t)(m0 + r) * DD + k0 + c * 8;
            f32x4 x0 = *(const f32x4*)xp;
            f32x4 x1 = *(const f32x4*)(xp + 4);
            s16x8 av;
            av[0] = (short)f2bf(x0[0]); av[1] = (short)f2bf(x0[1]);
            av[2] = (short)f2bf(x0[2]); av[3] = (short)f2bf(x0[3]);
            av[4] = (short)f2bf(x1[0]); av[5] = (short)f2bf(x1[1]);
            av[6] = (short)f2bf(x1[2]); av[7] = (short)f2bf(x1[3]);
            *(s16x8*)&lds[r * 32 + ((c ^ (r & 3)) * 8)] = av;
        }
        {
            float t[16];
            #pragma unroll
            for (int j = 0; j < 16; ++j) t[j] = wsrc[(size_t)(k0 + bk + j) * ldw];
            #pragma unroll
            for (int jj = 0; jj < 2; ++jj) {
                s16x8 bv;
                #pragma unroll
                for (int j = 0; j < 8; ++j) bv[j] = (short)f2bf(t[jj * 8 + j]);
                const int ch = (tid >> 7) * 2 + jj;
                *(s16x8*)&lds[4096 + bn * 32 + ((ch ^ (bn & 3)) * 8)] = bv;
            }
        }
        __syncthreads();

        s16x8 af[4], bf[4];
        #pragma unroll
        for (int rt = 0; rt < 4; ++rt) {
            const int row = wr * 64 + rt * 16 + si;
            af[rt] = *(const s16x8*)&lds[row * 32 + ((qq ^ (row & 3)) * 8)];
        }
        #pragma unroll
        for (int ct = 0; ct < 4; ++ct) {
            const int col = wc * 64 + ct * 16 + si;
            bf[ct] = *(const s16x8*)&lds[4096 + col * 32 + ((qq ^ (col & 3)) * 8)];
        }
        #pragma unroll
        for (int rt = 0; rt < 4; ++rt)
            #pragma unroll
            for (int ct = 0; ct < 4; ++ct)
                acc[rt][ct] = __builtin_amdgcn_mfma_f32_16x16x32_bf16(af[rt], bf[ct], acc[rt][ct], 0, 0, 0);
        __syncthreads();
    }

    if (nb == 0) {
        if (wc == 0) {  // q: natural layout, fold 1/sqrt(K)
            #pragma unroll
            for (int rt = 0; rt < 4; ++rt)
                #pragma unroll
                for (int ct = 0; ct < 4; ++ct)
                    #pragma unroll
                    for (int r = 0; r < 4; ++r) {
                        const int m = m0 + wr * 64 + rt * 16 + qq * 4 + r;
                        qo[(size_t)m * 64 + ct * 16 + si] = f2bf(acc[rt][ct][r] * 0.125f);
                    }
        } else {        // k: pre-swizzled (chunk c -> c ^ (t&7))
            #pragma unroll
            for (int rt = 0; rt < 4; ++rt)
                #pragma unroll
                for (int ct = 0; ct < 4; ++ct)
                    #pragma unroll
                    for (int r = 0; r < 4; ++r) {
                        const int m = m0 + wr * 64 + rt * 16 + qq * 4 + r;
                        const int col = ct * 16 + si;
                        ko[(size_t)m * 64 + (((col >> 3) ^ (m & 7)) * 8) + (col & 7)] = f2bf(acc[rt][ct][r]);
                    }
        }
    } else {
        #pragma unroll
        for (int rt = 0; rt < 4; ++rt)
            #pragma unroll
            for (int ct = 0; ct < 4; ++ct)
                #pragma unroll
                for (int r = 0; r < 4; ++r) {
                    const int m = wr * 64 + rt * 16 + qq * 4 + r;
                    const int n = wc * 64 + ct * 16 + si;
                    lds[n * 128 + (((m >> 3) ^ (n & 7)) * 8) + (m & 7)] = f2bf(acc[rt][ct][r]);
                }
        __syncthreads();
        const int bbat = m0 >> 11, t0 = m0 & 2047;
        #pragma unroll
        for (int i = 0; i < 8; ++i) {
            const int u = tid + 256 * i, n = u >> 4, mc = u & 15;
            s16x8 v = *(const s16x8*)&lds[n * 128 + ((mc ^ (n & 7)) * 8)];
            *(s16x8*)&vto[((size_t)bbat * DD + ((nb - 1) * 128 + n)) * TT
                          + t0 + (mc >> 3) * 64 + (((mc & 7) ^ (n & 7)) * 8)] = v;
        }
    }
}

// ---------------- fused causal attention, P-computed-once, pipelined P, 256-thr ----------------
// Block = (bb, eh: 128 e-cols, q2: 64 q-rows). 4 waves: w = (qh: 32 q-rows, eg: 64 e-cols).
// Per s-tile (64): wave w PRODUCES P-subtile (qh=w>>1, ss=w&1) -> a-frags in LDS (exp'd, pk2+shfl
// packed, diag-masked); all waves CONSUME P(it-1) for PV (pipelined 1 iter behind -> single
// barrier/iter, staging stays async). V triple-buffered vl[it%3] (PV reads it-1 while it+1 stages);
// K double-buffered; P double-buffered. LDS = 16+48+16 = 80KB -> 2 blocks/CU, 8 waves/CU.
// Grid 768 = 8 bb (g&7 -> one batch per XCD, K/V L2-resident) x 3 eh x 32 q2 DESCENDING (LPT:
// 512 resident, light blocks backfill).
__global__ __launch_bounds__(256, 2) void attn(
    const unsigned short* __restrict__ qg, const unsigned short* __restrict__ kg,
    const unsigned short* __restrict__ vg, float* __restrict__ out)
{
    // ush map: kl [0,8192) = 2 x [64 t][64] | vl [8192,32768) = 3 x [128 e][64 t]
    //          pl [32768,40960) = 2 x [2 qh][2 ss][a0:512|a1:512] | stL overlays pl after loop
    __shared__ __align__(16) unsigned short lds[40960];

    const int tid = threadIdx.x;
    const int l   = tid & 63;
    const int w   = tid >> 6;    // 0..3
    const int qh  = w >> 1;      // 32-row q half
    const int eg  = w & 1;       // 64-col e group; doubles as produced s-subtile ss
    const int lo  = l & 31;
    const int hi  = l >> 5;

    const int g    = blockIdx.x;          // 0..767
    const int bb   = g & 7;
    const int rest = g >> 3;              // 0..95
    const int eh   = rest % 3;
    const int q2   = 31 - rest / 3;       // descending work (LPT)
    const int q0   = q2 * 64;
    const int e0   = eh * 128;
    const int qrow = q0 + qh * 32 + lo;

    // Q as B-operand frags (pre-scaled 1/8, natural layout)
    s16x8 qf[4];
    {
        const unsigned short* qp = qg + ((size_t)bb * TT + qrow) * 64;
        #pragma unroll
        for (int st = 0; st < 4; ++st) qf[st] = *(const s16x8*)(qp + st * 16 + hi * 8);
    }

    f32x16 o[2];
    #pragma unroll
    for (int et = 0; et < 2; ++et)
        #pragma unroll
        for (int r = 0; r < 16; ++r) o[et][r] = 0.f;
    float lp = 0.f;

    const unsigned short* kbase = kg + (size_t)bb * TT * 64;
    const unsigned short* vbase = vg + ((size_t)bb * DD + e0) * TT;

    // staging: K 8 chunks (2/wave) + V 16 chunks (4/wave), 1KB each
    #define STAGE(IT, KB, VB)                                                              \
    {                                                                                      \
        GLLDS(kbase + (size_t)(IT) * 4096 + (2 * w) * 512 + l * 8,                         \
              &lds[(KB) * 4096 + (2 * w) * 512]);                                          \
        GLLDS(kbase + (size_t)(IT) * 4096 + (2 * w + 1) * 512 + l * 8,                     \
              &lds[(KB) * 4096 + (2 * w + 1) * 512]);                                      \
        _Pragma("unroll")                                                                  \
        for (int c3 = 0; c3 < 4; ++c3) {                                                   \
            const int rg = 4 * w + c3;                                                     \
            GLLDS(vbase + (size_t)(rg * 8 + (l >> 3)) * TT + (IT) * 64 + (l & 7) * 8,      \
                  &lds[8192 + (VB) * 8192 + rg * 512]);                                    \
        }                                                                                  \
    }

    // PV consume of s-tile JT from vl[VB], pl[PB]
    #define PVSTEP(VB, PB)                                                                 \
    {                                                                                      \
        _Pragma("unroll")                                                                  \
        for (int ss = 0; ss < 2; ++ss) {                                                   \
            s16x8 a0 = *(const s16x8*)&lds[32768 + (PB) * 4096 + (qh * 2 + ss) * 1024 + l * 8];       \
            s16x8 a1 = *(const s16x8*)&lds[32768 + (PB) * 4096 + (qh * 2 + ss) * 1024 + 512 + l * 8]; \
            _Pragma("unroll")                                                              \
            for (int et = 0; et < 2; ++et) {                                               \
                const int el = eg * 64 + et * 32 + lo;                                     \
                const int vbse = 8192 + (VB) * 8192 + el * 64;                             \
                s16x8 v0 = *(const s16x8*)&lds[vbse + (((ss * 4 + hi) ^ (el & 7)) * 8)];   \
                o[et] = __builtin_amdgcn_mfma_f32_32x32x16_bf16(a0, v0, o[et], 0, 0, 0);   \
                s16x8 v1 = *(const s16x8*)&lds[vbse + (((ss * 4 + 2 + hi) ^ (el & 7)) * 8)]; \
                o[et] = __builtin_amdgcn_mfma_f32_32x32x16_bf16(a1, v1, o[et], 0, 0, 0);   \
            }                                                                              \
        }                                                                                  \
    }

    STAGE(0, 0, 0);   // prologue: tile 0 -> kl0 / vl0

    int vi = 0, vn = 1;   // vl index of tile it, it+1 (mod 3); tile it-1 sits at the third slot
    for (int it = 0; it <= q2; ++it) {
        const int kb = it & 1;
        __syncthreads();   // vmcnt(0)+barrier: staging for tile it complete; pl[kb] free to overwrite

        if (it < q2) STAGE(it + 1, 1 - kb, vn);   // in flight through the whole compute phase

        // ---- produce P-subtile (qh, ss=eg) of tile it -> pl[kb] ----
        {
            f32x16 sa;
            #pragma unroll
            for (int r = 0; r < 16; ++r) sa[r] = 0.f;
            #pragma unroll
            for (int st = 0; st < 4; ++st) {
                s16x8 kf = *(const s16x8*)&lds[kb * 4096 + (eg * 32 + lo) * 64 + (((st * 2 + hi) ^ (lo & 7)) * 8)];
                sa = __builtin_amdgcn_mfma_f32_32x32x16_bf16(kf, qf[st], sa, 0, 0, 0);
            }
            const bool mb = (it == q2);
            float pv[16];
            #pragma unroll
            for (int r = 0; r < 16; ++r) {
                float e = __expf(sa[r]);
                if (mb) {
                    const int srow = it * 64 + eg * 32 + (r & 3) + 8 * (r >> 2) + 4 * hi;
                    if (srow > qrow) e = 0.f;
                }
                pv[r] = e;
                lp += e;
            }
            unsigned int d0 = pk2(pv[0], pv[1]),   d1 = pk2(pv[2], pv[3]);
            unsigned int d2 = pk2(pv[4], pv[5]),   d3 = pk2(pv[6], pv[7]);
            unsigned int d4 = pk2(pv[8], pv[9]),   d5 = pk2(pv[10], pv[11]);
            unsigned int d6 = pk2(pv[12], pv[13]), d7 = pk2(pv[14], pv[15]);
            unsigned int sA0 = hi ? d0 : d2, sA1 = hi ? d1 : d3;
            unsigned int rA0 = (unsigned int)__shfl_xor((int)sA0, 32);
            unsigned int rA1 = (unsigned int)__shfl_xor((int)sA1, 32);
            u32x4 fa0 = hi ? (u32x4){rA0, rA1, d2, d3} : (u32x4){d0, d1, rA0, rA1};
            unsigned int sB0 = hi ? d4 : d6, sB1 = hi ? d5 : d7;
            unsigned int rB0 = (unsigned int)__shfl_xor((int)sB0, 32);
            unsigned int rB1 = (unsigned int)__shfl_xor((int)sB1, 32);
            u32x4 fa1 = hi ? (u32x4){rB0, rB1, d6, d7} : (u32x4){d4, d5, rB0, rB1};
            *(s16x8*)&lds[32768 + kb * 4096 + (qh * 2 + eg) * 1024 + l * 8]       = __builtin_bit_cast(s16x8, fa0);
            *(s16x8*)&lds[32768 + kb * 4096 + (qh * 2 + eg) * 1024 + 512 + l * 8] = __builtin_bit_cast(s16x8, fa1);
        }

        // ---- consume P of tile it-1 (written last iter; visible since barrier) ----
        if (it > 0) {
            const int vp = (vi == 0) ? 2 : vi - 1;
            PVSTEP(vp, 1 - kb);
        }

        vi = vn; vn = (vn == 2) ? 0 : vn + 1;
    }
    __syncthreads();           // last pl writes visible to all waves
    {
        const int vlast = (vi == 0) ? 2 : vi - 1;   // vl slot of tile q2
        PVSTEP(vlast, q2 & 1);
    }
    __syncthreads();           // all PV reads of pl done before stL overlays it

    // row sums: wave (qh, eg) holds lp for rows qh*32+lo over s-subtiles ss=eg
    float* stL = (float*)&lds[32768];   // [2 qh][2 ss][32]
    lp += __shfl_xor(lp, 32);
    if (hi == 0) stL[(qh * 2 + eg) * 32 + lo] = lp;
    __syncthreads();

    #pragma unroll
    for (int et = 0; et < 2; ++et)
        #pragma unroll
        for (int r = 0; r < 16; ++r) {
            const int rloc = (r & 3) + 8 * (r >> 2) + 4 * hi;
            const float linv = 1.f / (stL[qh * 64 + rloc] + stL[qh * 64 + 32 + rloc]);
            out[((size_t)bb * TT + q0 + qh * 32 + rloc) * DD + e0 + eg * 64 + et * 32 + lo]
                = o[et][r] * linv;
        }
    #undef STAGE
    #undef PVSTEP
}

extern "C" void kernel_launch(void* const* d_in, const int* in_sizes, int n_in,
                              void* d_out, int out_size, void* d_ws, size_t ws_size,
                              hipStream_t stream)
{
    const float* x  = (const float*)d_in[0];
    const float* Wq = (const float*)d_in[1];
    const float* Wk = (const float*)d_in[2];
    const float* Wv = (const float*)d_in[3];

    // ws: q [0,2M) | k [2M,4M) | vT [4M,16M)
    unsigned short* qws  = (unsigned short*)d_ws;
    unsigned short* kws  = (unsigned short*)((char*)d_ws + ((size_t)2 << 20));
    unsigned short* vtws = (unsigned short*)((char*)d_ws + ((size_t)4 << 20));

    qkv_gemm<<<dim3(128, 4), dim3(256), 0, stream>>>(x, Wq, Wk, Wv, qws, kws, vtws);
    attn<<<dim3(768), dim3(256), 0, stream>>>(qws, kws, vtws, (float*)d_out);
}